// Round 20
// baseline (89.792 us; speedup 1.0000x reference)
//
#include <hip/hip_runtime.h>

#define BB   256
#define NIMG 49
#define NGPS 32
#define DIM  256
#define MPAD 64

typedef __attribute__((ext_vector_type(8))) __bf16 bf16x8;
typedef __attribute__((ext_vector_type(4))) float  f32x4;
typedef __attribute__((ext_vector_type(4))) unsigned int u32x4;

__device__ inline unsigned short f2bf(float f) {
  unsigned int u = __float_as_uint(f);
  u += 0x7fff + ((u >> 16) & 1);   // round-to-nearest-even
  return (unsigned short)(u >> 16);
}

__device__ inline float max3f(float a, float b, float c) {
  return fmaxf(fmaxf(a, b), c);    // clang folds to v_max3_f32
}

// DPP cross-lane reduce helpers (VALU pipe, no DS traffic).
template<int CTRL>
__device__ inline float dppmax(float v) {
  float o = __int_as_float(__builtin_amdgcn_update_dpp(0, __float_as_int(v), CTRL, 0xF, 0xF, true));
  return fmaxf(v, o);
}
template<int CTRL>
__device__ inline float dppadd(float v) {
  float o = __int_as_float(__builtin_amdgcn_update_dpp(0, __float_as_int(v), CTRL, 0xF, 0xF, true));
  return v + o;
}
__device__ inline float max16(float v) {   // max across the 16 lanes of a DPP row
  v = dppmax<0xB1>(v); v = dppmax<0x4E>(v); v = dppmax<0x141>(v); v = dppmax<0x140>(v);
  return v;
}
__device__ inline float sum16(float v) {   // sum across the 16 lanes of a DPP row
  v = dppadd<0xB1>(v); v = dppadd<0x4E>(v); v = dppadd<0x141>(v); v = dppadd<0x140>(v);
  return v;
}

// ---------------- kernel 1: L2-normalize + cast to bf16, FRAGMENT-CONTIGUOUS layout --
//   imgS  [b][chunk s=0..31][row 0..63][8 bf16]   (b stride 16384 elem)
//   gpsS  [g][mt][kc][grp*16+c][8 bf16]           (g stride 8192 elem)
//   img48F[kc][bt=b>>4][lane][8 bf16]             (B-operand frags of img[b][48]; nullable)
__global__ __launch_bounds__(256) void norm_kernel(
    const float* __restrict__ img, const float* __restrict__ gps,
    unsigned short* __restrict__ imgS, unsigned short* __restrict__ gpsS,
    unsigned short* __restrict__ img48F)
{
  int w    = (blockIdx.x * 256 + threadIdx.x) >> 6;  // one wave per row
  int lane = threadIdx.x & 63;

  f32x4 x = (f32x4){0.f, 0.f, 0.f, 0.f};
  bool isimg; int b = 0, n = 0, g = 0, m = 0;
  if (w < BB * MPAD) {
    isimg = true; b = w >> 6; n = w & 63;
    if (n < NIMG)
      x = *reinterpret_cast<const f32x4*>(img + ((size_t)b * NIMG + n) * DIM + lane * 4);
  } else {
    isimg = false; int t = w - BB * MPAD; g = t >> 5; m = t & 31;
    x = *reinterpret_cast<const f32x4*>(gps + (size_t)t * DIM + lane * 4);
  }

  float ss = x[0]*x[0] + x[1]*x[1] + x[2]*x[2] + x[3]*x[3];
  #pragma unroll
  for (int d = 1; d < 64; d <<= 1) ss += __shfl_xor(ss, d);
  float inv = (ss > 0.f) ? (1.0f / fmaxf(sqrtf(ss), 1e-12f)) : 0.f;

  unsigned int w01 = (unsigned)f2bf(x[0]*inv) | ((unsigned)f2bf(x[1]*inv) << 16);
  unsigned int w23 = (unsigned)f2bf(x[2]*inv) | ((unsigned)f2bf(x[3]*inv) << 16);

  // lane L (<32) gathers chunk L = row elems [8L, 8L+8) from lanes 2L, 2L+1
  int L = lane;
  unsigned int a0 = __shfl(w01, 2 * L);
  unsigned int a1 = __shfl(w23, 2 * L);
  unsigned int a2 = __shfl(w01, 2 * L + 1);
  unsigned int a3 = __shfl(w23, 2 * L + 1);
  if (L < 32) {
    u32x4 v = {a0, a1, a2, a3};
    if (isimg) {
      *reinterpret_cast<u32x4*>(imgS + (size_t)b * 16384 + L * 512 + n * 8) = v;
      if (n == 48 && img48F) {        // B-frag: col=b, k-chunk kc=L>>2, sub grp=L&3
        unsigned short* d48 = img48F + ((L >> 2) * 16 + (b >> 4)) * 512
                                     + ((L & 3) * 16 + (b & 15)) * 8;
        *reinterpret_cast<u32x4*>(d48) = v;
      }
    } else {
      int mt = m >> 4, c = m & 15, kc = L >> 2, grp = L & 3;
      *reinterpret_cast<u32x4*>(
          gpsS + (size_t)g * 8192 + mt * 4096 + kc * 512 + (grp * 16 + c) * 8) = v;
    }
  }
}

// ---------------- kernel 1b: S48[g][b][m] = gps[g,m] . img[b,48]  (dense MFMA) -------
// 8192 wave-tasks: t = g*2+mt (512), bt = b-tile (16). One 16x16 tile each.
__global__ __launch_bounds__(256) void gemm48_kernel(
    const unsigned short* __restrict__ gpsS, const unsigned short* __restrict__ img48F,
    float* __restrict__ S48)
{
  int wv = threadIdx.x >> 6, lane = threadIdx.x & 63;
  int id = blockIdx.x * 4 + wv;            // 0..8191
  int t  = id >> 4, bt = id & 15;
  const unsigned short* ga = gpsS  + (size_t)t * 4096 + lane * 8;
  const unsigned short* bb = img48F + bt * 512 + lane * 8;

  f32x4 acc = (f32x4){0.f, 0.f, 0.f, 0.f};
  #pragma unroll
  for (int kc = 0; kc < 8; ++kc) {
    bf16x8 a = *reinterpret_cast<const bf16x8*>(ga + kc * 512);
    bf16x8 q = *reinterpret_cast<const bf16x8*>(bb + kc * 8192);   // [kc][bt] stride 16*512
    acc = __builtin_amdgcn_mfma_f32_16x16x32_bf16(a, q, acc, 0, 0, 0);
  }
  int grp = lane >> 4, c = lane & 15;
  int g = t >> 1, mbase = (t & 1) * 16 + grp * 4, b = bt * 16 + c;
  *reinterpret_cast<f32x4*>(S48 + (size_t)g * 8192 + b * 32 + mbase) = acc;
}

// ---------------- kernel 2 (NEW): 3-hf pair kernel + S48 merge -----------------------
// hf3 (1 valid col of 16) removed: 48 MFMAs/pair (-25%), acc 48 AGPR -> (256,4)
// gives 4 waves/SIMD. n=48 contributions merged from S48 via 2 broadcast f32x4 loads.
// LDS 24KB. kc `unroll 1` (liveness throttle, r14 lesson). Spill guard: WRITE ~0.5MB.
__global__ __launch_bounds__(256, 4) void pair3_kernel(
    const unsigned short* __restrict__ imgS, const unsigned short* __restrict__ gpsS,
    const float* __restrict__ S48,
    float* __restrict__ i2g, float* __restrict__ g2i)
{
  int tid  = threadIdx.x;
  int wv   = tid >> 6;
  int lane = tid & 63;
  int c    = lane & 15, grp = lane >> 4;
  int b    = blockIdx.x >> 3, gc = blockIdx.x & 7;
  int wvu  = __builtin_amdgcn_readfirstlane(wv);

  __shared__ unsigned short As[8 * 3 * 64 * 8];    // [kc][hf<3][lane][8] = 24 KB

  {  // stage: wave wvu covers kc = wvu*2 + i/3, hf = i%3  (24 combos total)
    const unsigned short* src = imgS + (size_t)b * 16384;
    #pragma unroll
    for (int i = 0; i < 6; ++i) {
      int kc = wvu * 2 + (i / 3), hf = i % 3;
      bf16x8 v = *reinterpret_cast<const bf16x8*>(
          src + (kc * 4 + grp) * 512 + (hf * 16 + c) * 8);
      *reinterpret_cast<bf16x8*>(
          reinterpret_cast<char*>(As) + (kc * 3 + hf) * 1024 + lane * 16) = v;
    }
  }
  __syncthreads();

  const char* ab = reinterpret_cast<const char*>(As) + lane * 16;
  const unsigned short* gb = gpsS + ((size_t)(gc * 32 + wvu * 8)) * 8192;
  unsigned int lane8 = lane * 8;

  #pragma unroll 1
  for (int st = 0; st < 4; ++st) {
    f32x4 acc[2][2][3];                    // [g][mt][hf<3]

    {  // peeled kc=0, shared zero C
      const unsigned short* p = gb + lane8;
      bf16x8 q00 = *reinterpret_cast<const bf16x8*>(p);
      bf16x8 q01 = *reinterpret_cast<const bf16x8*>(p + 4096);
      bf16x8 q10 = *reinterpret_cast<const bf16x8*>(p + 8192);
      bf16x8 q11 = *reinterpret_cast<const bf16x8*>(p + 12288);
      bf16x8 a0 = *reinterpret_cast<const bf16x8*>(ab);
      bf16x8 a1 = *reinterpret_cast<const bf16x8*>(ab + 1024);
      bf16x8 a2 = *reinterpret_cast<const bf16x8*>(ab + 2048);
      const f32x4 Z = {0.f, 0.f, 0.f, 0.f};
      acc[0][0][0] = __builtin_amdgcn_mfma_f32_16x16x32_bf16(q00, a0, Z, 0, 0, 0);
      acc[0][0][1] = __builtin_amdgcn_mfma_f32_16x16x32_bf16(q00, a1, Z, 0, 0, 0);
      acc[0][0][2] = __builtin_amdgcn_mfma_f32_16x16x32_bf16(q00, a2, Z, 0, 0, 0);
      acc[0][1][0] = __builtin_amdgcn_mfma_f32_16x16x32_bf16(q01, a0, Z, 0, 0, 0);
      acc[0][1][1] = __builtin_amdgcn_mfma_f32_16x16x32_bf16(q01, a1, Z, 0, 0, 0);
      acc[0][1][2] = __builtin_amdgcn_mfma_f32_16x16x32_bf16(q01, a2, Z, 0, 0, 0);
      acc[1][0][0] = __builtin_amdgcn_mfma_f32_16x16x32_bf16(q10, a0, Z, 0, 0, 0);
      acc[1][0][1] = __builtin_amdgcn_mfma_f32_16x16x32_bf16(q10, a1, Z, 0, 0, 0);
      acc[1][0][2] = __builtin_amdgcn_mfma_f32_16x16x32_bf16(q10, a2, Z, 0, 0, 0);
      acc[1][1][0] = __builtin_amdgcn_mfma_f32_16x16x32_bf16(q11, a0, Z, 0, 0, 0);
      acc[1][1][1] = __builtin_amdgcn_mfma_f32_16x16x32_bf16(q11, a1, Z, 0, 0, 0);
      acc[1][1][2] = __builtin_amdgcn_mfma_f32_16x16x32_bf16(q11, a2, Z, 0, 0, 0);
    }

    #pragma unroll 1
    for (int kc = 1; kc < 8; ++kc) {
      const unsigned short* p = gb + kc * 512 + lane8;
      bf16x8 q00 = *reinterpret_cast<const bf16x8*>(p);
      bf16x8 q01 = *reinterpret_cast<const bf16x8*>(p + 4096);
      bf16x8 q10 = *reinterpret_cast<const bf16x8*>(p + 8192);
      bf16x8 q11 = *reinterpret_cast<const bf16x8*>(p + 12288);
      const char* ak = ab + kc * 3072;
      bf16x8 a0 = *reinterpret_cast<const bf16x8*>(ak);
      bf16x8 a1 = *reinterpret_cast<const bf16x8*>(ak + 1024);
      bf16x8 a2 = *reinterpret_cast<const bf16x8*>(ak + 2048);
      acc[0][0][0] = __builtin_amdgcn_mfma_f32_16x16x32_bf16(q00, a0, acc[0][0][0], 0, 0, 0);
      acc[0][0][1] = __builtin_amdgcn_mfma_f32_16x16x32_bf16(q00, a1, acc[0][0][1], 0, 0, 0);
      acc[0][0][2] = __builtin_amdgcn_mfma_f32_16x16x32_bf16(q00, a2, acc[0][0][2], 0, 0, 0);
      acc[0][1][0] = __builtin_amdgcn_mfma_f32_16x16x32_bf16(q01, a0, acc[0][1][0], 0, 0, 0);
      acc[0][1][1] = __builtin_amdgcn_mfma_f32_16x16x32_bf16(q01, a1, acc[0][1][1], 0, 0, 0);
      acc[0][1][2] = __builtin_amdgcn_mfma_f32_16x16x32_bf16(q01, a2, acc[0][1][2], 0, 0, 0);
      acc[1][0][0] = __builtin_amdgcn_mfma_f32_16x16x32_bf16(q10, a0, acc[1][0][0], 0, 0, 0);
      acc[1][0][1] = __builtin_amdgcn_mfma_f32_16x16x32_bf16(q10, a1, acc[1][0][1], 0, 0, 0);
      acc[1][0][2] = __builtin_amdgcn_mfma_f32_16x16x32_bf16(q10, a2, acc[1][0][2], 0, 0, 0);
      acc[1][1][0] = __builtin_amdgcn_mfma_f32_16x16x32_bf16(q11, a0, acc[1][1][0], 0, 0, 0);
      acc[1][1][1] = __builtin_amdgcn_mfma_f32_16x16x32_bf16(q11, a1, acc[1][1][1], 0, 0, 0);
      acc[1][1][2] = __builtin_amdgcn_mfma_f32_16x16x32_bf16(q11, a2, acc[1][1][2], 0, 0, 0);
    }

    // ---- epilogue: D = S^T, row m = mt*16+grp*4+r, col n = hf*16+c; n=48 from S48 ----
    #pragma unroll
    for (int g = 0; g < 2; ++g) {
      int gg = gc * 32 + wvu * 8 + st * 2 + g;
      const float* sp = S48 + (size_t)gg * 8192 + b * 32 + grp * 4;
      f32x4 sa = *reinterpret_cast<const f32x4*>(sp);        // m = grp*4 + r      (mt0)
      f32x4 sb = *reinterpret_cast<const f32x4*>(sp + 16);   // m = 16 + grp*4 + r (mt1)

      // i2g: mean over n<49 of (max over m)
      float vmax[3];
      #pragma unroll
      for (int hf = 0; hf < 3; ++hf) {
        float vm = fmaxf(max3f(acc[g][0][hf][0], acc[g][0][hf][1], acc[g][0][hf][2]),
                         max3f(acc[g][0][hf][3], acc[g][1][hf][0], acc[g][1][hf][1]));
        vm = max3f(vm, acc[g][1][hf][2], acc[g][1][hf][3]);
        vm = fmaxf(vm, __shfl_xor(vm, 16));
        vm = fmaxf(vm, __shfl_xor(vm, 32));
        vmax[hf] = vm;
      }
      float s = vmax[0] + vmax[1] + vmax[2];
      s = sum16(s);                          // sum over c -> cols 0..47
      float m48 = fmaxf(max3f(sa[0], sa[1], sa[2]),
                        max3f(sa[3], sb[0], sb[1]));
      m48 = max3f(m48, sb[2], sb[3]);
      m48 = fmaxf(m48, __shfl_xor(m48, 16));
      m48 = fmaxf(m48, __shfl_xor(m48, 32)); // max over m (grp spread)
      s += m48;                              // col 48's row-max

      // g2i: mean over 32 m of (max over n<49)
      float t = 0.f;
      #pragma unroll
      for (int mt = 0; mt < 2; ++mt)
        #pragma unroll
        for (int r = 0; r < 4; ++r) {
          float s48v = (mt == 0) ? sa[r] : sb[r];
          float hm = fmaxf(max3f(acc[g][mt][0][r], acc[g][mt][1][r], acc[g][mt][2][r]), s48v);
          hm = max16(hm);
          t += hm;
        }
      t += __shfl_xor(t, 16);
      t += __shfl_xor(t, 32);

      if (lane == 0) {
        i2g[b * 256 + gg] = s * (1.0f / NIMG);
        g2i[gg * 256 + b] = t * (1.0f / NGPS);
      }
    }
    gb += 16384;
  }
}

// ---------------- kernel 2 (FALLBACK = r16 verified): 4-hf pair kernel ---------------
__global__ __launch_bounds__(256, 3) void pair4_kernel(
    const unsigned short* __restrict__ imgS, const unsigned short* __restrict__ gpsS,
    float* __restrict__ i2g, float* __restrict__ g2i)
{
  int tid  = threadIdx.x;
  int wv   = tid >> 6;
  int lane = tid & 63;
  int c    = lane & 15;
  int b    = blockIdx.x >> 3, gc = blockIdx.x & 7;
  int wvu  = __builtin_amdgcn_readfirstlane(wv);

  __shared__ unsigned short As[8 * 4 * 64 * 8];    // 32 KB

  {
    const unsigned short* src = imgS + (size_t)b * 16384;
    #pragma unroll
    for (int i = 0; i < 8; ++i) {
      bf16x8 v = *reinterpret_cast<const bf16x8*>(
          src + (i * 4 + (lane >> 4)) * 512 + (wvu * 16 + (lane & 15)) * 8);
      *reinterpret_cast<bf16x8*>(
          reinterpret_cast<char*>(As) + i * 4096 + wvu * 1024 + lane * 16) = v;
    }
  }
  __syncthreads();

  const char* ab = reinterpret_cast<const char*>(As) + lane * 16;
  const unsigned short* gb = gpsS + ((size_t)(gc * 32 + wvu * 8)) * 8192;
  unsigned int lane8 = lane * 8;

  #pragma unroll 1
  for (int st = 0; st < 4; ++st) {
    f32x4 acc[2][2][4];
    {
      const unsigned short* p = gb + lane8;
      bf16x8 q00 = *reinterpret_cast<const bf16x8*>(p);
      bf16x8 q01 = *reinterpret_cast<const bf16x8*>(p + 4096);
      bf16x8 q10 = *reinterpret_cast<const bf16x8*>(p + 8192);
      bf16x8 q11 = *reinterpret_cast<const bf16x8*>(p + 12288);
      bf16x8 a0 = *reinterpret_cast<const bf16x8*>(ab);
      bf16x8 a1 = *reinterpret_cast<const bf16x8*>(ab + 1024);
      bf16x8 a2 = *reinterpret_cast<const bf16x8*>(ab + 2048);
      bf16x8 a3 = *reinterpret_cast<const bf16x8*>(ab + 3072);
      const f32x4 Z = {0.f, 0.f, 0.f, 0.f};
      acc[0][0][0] = __builtin_amdgcn_mfma_f32_16x16x32_bf16(q00, a0, Z, 0, 0, 0);
      acc[0][0][1] = __builtin_amdgcn_mfma_f32_16x16x32_bf16(q00, a1, Z, 0, 0, 0);
      acc[0][0][2] = __builtin_amdgcn_mfma_f32_16x16x32_bf16(q00, a2, Z, 0, 0, 0);
      acc[0][0][3] = __builtin_amdgcn_mfma_f32_16x16x32_bf16(q00, a3, Z, 0, 0, 0);
      acc[0][1][0] = __builtin_amdgcn_mfma_f32_16x16x32_bf16(q01, a0, Z, 0, 0, 0);
      acc[0][1][1] = __builtin_amdgcn_mfma_f32_16x16x32_bf16(q01, a1, Z, 0, 0, 0);
      acc[0][1][2] = __builtin_amdgcn_mfma_f32_16x16x32_bf16(q01, a2, Z, 0, 0, 0);
      acc[0][1][3] = __builtin_amdgcn_mfma_f32_16x16x32_bf16(q01, a3, Z, 0, 0, 0);
      acc[1][0][0] = __builtin_amdgcn_mfma_f32_16x16x32_bf16(q10, a0, Z, 0, 0, 0);
      acc[1][0][1] = __builtin_amdgcn_mfma_f32_16x16x32_bf16(q10, a1, Z, 0, 0, 0);
      acc[1][0][2] = __builtin_amdgcn_mfma_f32_16x16x32_bf16(q10, a2, Z, 0, 0, 0);
      acc[1][0][3] = __builtin_amdgcn_mfma_f32_16x16x32_bf16(q10, a3, Z, 0, 0, 0);
      acc[1][1][0] = __builtin_amdgcn_mfma_f32_16x16x32_bf16(q11, a0, Z, 0, 0, 0);
      acc[1][1][1] = __builtin_amdgcn_mfma_f32_16x16x32_bf16(q11, a1, Z, 0, 0, 0);
      acc[1][1][2] = __builtin_amdgcn_mfma_f32_16x16x32_bf16(q11, a2, Z, 0, 0, 0);
      acc[1][1][3] = __builtin_amdgcn_mfma_f32_16x16x32_bf16(q11, a3, Z, 0, 0, 0);
    }
    #pragma unroll 1
    for (int kc = 1; kc < 8; ++kc) {
      const unsigned short* p = gb + kc * 512 + lane8;
      bf16x8 q00 = *reinterpret_cast<const bf16x8*>(p);
      bf16x8 q01 = *reinterpret_cast<const bf16x8*>(p + 4096);
      bf16x8 q10 = *reinterpret_cast<const bf16x8*>(p + 8192);
      bf16x8 q11 = *reinterpret_cast<const bf16x8*>(p + 12288);
      const char* ak = ab + kc * 4096;
      bf16x8 a0 = *reinterpret_cast<const bf16x8*>(ak);
      bf16x8 a1 = *reinterpret_cast<const bf16x8*>(ak + 1024);
      bf16x8 a2 = *reinterpret_cast<const bf16x8*>(ak + 2048);
      bf16x8 a3 = *reinterpret_cast<const bf16x8*>(ak + 3072);
      acc[0][0][0] = __builtin_amdgcn_mfma_f32_16x16x32_bf16(q00, a0, acc[0][0][0], 0, 0, 0);
      acc[0][0][1] = __builtin_amdgcn_mfma_f32_16x16x32_bf16(q00, a1, acc[0][0][1], 0, 0, 0);
      acc[0][0][2] = __builtin_amdgcn_mfma_f32_16x16x32_bf16(q00, a2, acc[0][0][2], 0, 0, 0);
      acc[0][0][3] = __builtin_amdgcn_mfma_f32_16x16x32_bf16(q00, a3, acc[0][0][3], 0, 0, 0);
      acc[0][1][0] = __builtin_amdgcn_mfma_f32_16x16x32_bf16(q01, a0, acc[0][1][0], 0, 0, 0);
      acc[0][1][1] = __builtin_amdgcn_mfma_f32_16x16x32_bf16(q01, a1, acc[0][1][1], 0, 0, 0);
      acc[0][1][2] = __builtin_amdgcn_mfma_f32_16x16x32_bf16(q01, a2, acc[0][1][2], 0, 0, 0);
      acc[0][1][3] = __builtin_amdgcn_mfma_f32_16x16x32_bf16(q01, a3, acc[0][1][3], 0, 0, 0);
      acc[1][0][0] = __builtin_amdgcn_mfma_f32_16x16x32_bf16(q10, a0, acc[1][0][0], 0, 0, 0);
      acc[1][0][1] = __builtin_amdgcn_mfma_f32_16x16x32_bf16(q10, a1, acc[1][0][1], 0, 0, 0);
      acc[1][0][2] = __builtin_amdgcn_mfma_f32_16x16x32_bf16(q10, a2, acc[1][0][2], 0, 0, 0);
      acc[1][0][3] = __builtin_amdgcn_mfma_f32_16x16x32_bf16(q10, a3, acc[1][0][3], 0, 0, 0);
      acc[1][1][0] = __builtin_amdgcn_mfma_f32_16x16x32_bf16(q11, a0, acc[1][1][0], 0, 0, 0);
      acc[1][1][1] = __builtin_amdgcn_mfma_f32_16x16x32_bf16(q11, a1, acc[1][1][1], 0, 0, 0);
      acc[1][1][2] = __builtin_amdgcn_mfma_f32_16x16x32_bf16(q11, a2, acc[1][1][2], 0, 0, 0);
      acc[1][1][3] = __builtin_amdgcn_mfma_f32_16x16x32_bf16(q11, a3, acc[1][1][3], 0, 0, 0);
    }
    #pragma unroll
    for (int g = 0; g < 2; ++g) {
      float vmax[4];
      #pragma unroll
      for (int hf = 0; hf < 4; ++hf) {
        float vm = fmaxf(max3f(acc[g][0][hf][0], acc[g][0][hf][1], acc[g][0][hf][2]),
                         max3f(acc[g][0][hf][3], acc[g][1][hf][0], acc[g][1][hf][1]));
        vm = max3f(vm, acc[g][1][hf][2], acc[g][1][hf][3]);
        vm = fmaxf(vm, __shfl_xor(vm, 16));
        vm = fmaxf(vm, __shfl_xor(vm, 32));
        vmax[hf] = vm;
      }
      float s = vmax[0] + vmax[1] + vmax[2] + ((c == 0) ? vmax[3] : 0.0f);
      s = sum16(s);
      float t = 0.f;
      #pragma unroll
      for (int mt = 0; mt < 2; ++mt)
        #pragma unroll
        for (int r = 0; r < 4; ++r) {
          float h3 = (c == 0) ? acc[g][mt][3][r] : -3.0e38f;
          float hm = fmaxf(max3f(acc[g][mt][0][r], acc[g][mt][1][r], acc[g][mt][2][r]), h3);
          hm = max16(hm);
          t += hm;
        }
      t += __shfl_xor(t, 16);
      t += __shfl_xor(t, 32);
      if (lane == 0) {
        int gg = gc * 32 + wvu * 8 + st * 2 + g;
        i2g[b * 256 + gg] = s * (1.0f / NIMG);
        g2i[gg * 256 + b] = t * (1.0f / NGPS);
      }
    }
    gb += 16384;
  }
}

// ---------------- kernel 3: per-row CE partials -------------------------------------
__global__ __launch_bounds__(256) void ce_kernel(
    const float* __restrict__ i2g, const float* __restrict__ g2i,
    const float* __restrict__ lsp, float* __restrict__ partial)
{
  int b = blockIdx.x, t = threadIdx.x, lane = t & 63, wv = t >> 6;
  float s = fminf(expf(lsp[0]), 100.0f);
  float v1 = s * i2g[b * 256 + t];
  float v2 = s * g2i[b * 256 + t];

  float m1 = v1, m2 = v2;
  #pragma unroll
  for (int d = 1; d < 64; d <<= 1) {
    m1 = fmaxf(m1, __shfl_xor(m1, d));
    m2 = fmaxf(m2, __shfl_xor(m2, d));
  }
  __shared__ float sm[2][4];
  if (lane == 0) { sm[0][wv] = m1; sm[1][wv] = m2; }
  __syncthreads();
  m1 = fmaxf(fmaxf(sm[0][0], sm[0][1]), fmaxf(sm[0][2], sm[0][3]));
  m2 = fmaxf(fmaxf(sm[1][0], sm[1][1]), fmaxf(sm[1][2], sm[1][3]));

  float e1 = expf(v1 - m1), e2 = expf(v2 - m2);
  #pragma unroll
  for (int d = 1; d < 64; d <<= 1) {
    e1 += __shfl_xor(e1, d);
    e2 += __shfl_xor(e2, d);
  }
  __shared__ float se[2][4];
  if (lane == 0) { se[0][wv] = e1; se[1][wv] = e2; }
  __syncthreads();
  if (t == 0) {
    float S1 = se[0][0] + se[0][1] + se[0][2] + se[0][3];
    float S2 = se[1][0] + se[1][1] + se[1][2] + se[1][3];
    float lse1 = m1 + logf(S1);
    float lse2 = m2 + logf(S2);
    partial[b] = (lse1 - s * i2g[b * 257]) + (lse2 - s * g2i[b * 257]);
  }
}

// ---------------- kernel 4: final scalar --------------------------------------------
__global__ __launch_bounds__(256) void finish_kernel(
    const float* __restrict__ partial, float* __restrict__ out)
{
  int t = threadIdx.x, lane = t & 63, wv = t >> 6;
  float v = partial[t];
  #pragma unroll
  for (int d = 1; d < 64; d <<= 1) v += __shfl_xor(v, d);
  __shared__ float sp[4];
  if (lane == 0) sp[wv] = v;
  __syncthreads();
  if (t == 0) out[0] = (sp[0] + sp[1] + sp[2] + sp[3]) * (1.0f / 512.0f);
}

extern "C" void kernel_launch(void* const* d_in, const int* in_sizes, int n_in,
                              void* d_out, int out_size, void* d_ws, size_t ws_size,
                              hipStream_t stream)
{
  const float* img = (const float*)d_in[0];
  const float* gps = (const float*)d_in[1];
  const float* lsp = (const float*)d_in[2];
  float* out = (float*)d_out;
  char* ws = (char*)d_ws;

  // New-path layout (needs 21,627,904 B). Falls back to r16 path if ws too small.
  const size_t NEED = 21627904;
  unsigned short* imgS = (unsigned short*)(ws);               //  8,388,608
  unsigned short* gpsS = (unsigned short*)(ws + 8388608);     //  4,194,304

  if (ws_size >= NEED) {
    unsigned short* img48F = (unsigned short*)(ws + 12582912); //   131,072
    float* S48     = (float*)(ws + 12713984);                  // 8,388,608
    float* i2g     = (float*)(ws + 21102592);                  //   262,144
    float* g2i     = (float*)(ws + 21364736);                  //   262,144
    float* partial = (float*)(ws + 21626880);                  //     1,024
    norm_kernel<<<6144, 256, 0, stream>>>(img, gps, imgS, gpsS, img48F);
    gemm48_kernel<<<2048, 256, 0, stream>>>(gpsS, img48F, S48);
    pair3_kernel<<<2048, 256, 0, stream>>>(imgS, gpsS, S48, i2g, g2i);
    ce_kernel<<<256, 256, 0, stream>>>(i2g, g2i, lsp, partial);
    finish_kernel<<<1, 256, 0, stream>>>(partial, out);
  } else {
    float* i2g     = (float*)(ws + 12582912);
    float* g2i     = (float*)(ws + 12845056);
    float* partial = (float*)(ws + 13107200);
    norm_kernel<<<6144, 256, 0, stream>>>(img, gps, imgS, gpsS, nullptr);
    pair4_kernel<<<2048, 256, 0, stream>>>(imgS, gpsS, i2g, g2i);
    ce_kernel<<<256, 256, 0, stream>>>(i2g, g2i, lsp, partial);
    finish_kernel<<<1, 256, 0, stream>>>(partial, out);
  }
}

// Round 21
// 89.381 us; speedup vs baseline: 1.0046x; 1.0046x over previous
//
#include <hip/hip_runtime.h>

#define BB   256
#define NIMG 49
#define NGPS 32
#define DIM  256
#define MPAD 64

typedef __attribute__((ext_vector_type(8))) __bf16 bf16x8;
typedef __attribute__((ext_vector_type(4))) float  f32x4;
typedef __attribute__((ext_vector_type(4))) unsigned int u32x4;

__device__ inline unsigned short f2bf(float f) {
  unsigned int u = __float_as_uint(f);
  u += 0x7fff + ((u >> 16) & 1);   // round-to-nearest-even
  return (unsigned short)(u >> 16);
}

__device__ inline float max3f(float a, float b, float c) {
  return fmaxf(fmaxf(a, b), c);    // clang folds to v_max3_f32
}

// DPP cross-lane reduce helpers (VALU pipe, no DS traffic).
template<int CTRL>
__device__ inline float dppmax(float v) {
  float o = __int_as_float(__builtin_amdgcn_update_dpp(0, __float_as_int(v), CTRL, 0xF, 0xF, true));
  return fmaxf(v, o);
}
template<int CTRL>
__device__ inline float dppadd(float v) {
  float o = __int_as_float(__builtin_amdgcn_update_dpp(0, __float_as_int(v), CTRL, 0xF, 0xF, true));
  return v + o;
}
__device__ inline float max16(float v) {   // max across the 16 lanes of a DPP row
  v = dppmax<0xB1>(v); v = dppmax<0x4E>(v); v = dppmax<0x141>(v); v = dppmax<0x140>(v);
  return v;
}
__device__ inline float sum16(float v) {   // sum across the 16 lanes of a DPP row
  v = dppadd<0xB1>(v); v = dppadd<0x4E>(v); v = dppadd<0x141>(v); v = dppadd<0x140>(v);
  return v;
}

// ---------------- kernel 1: L2-normalize + cast to bf16, FRAGMENT-CONTIGUOUS layout --
//   imgS  [b][chunk s=0..31][row 0..63][8 bf16]   (b stride 16384 elem)
//   gpsS  [g][mt][kc][grp*16+c][8 bf16]           (g stride 8192 elem)
//   img48F[kc][bt=b>>4][lane][8 bf16]             (B-operand frags of img[b][48]; nullable)
__global__ __launch_bounds__(256) void norm_kernel(
    const float* __restrict__ img, const float* __restrict__ gps,
    unsigned short* __restrict__ imgS, unsigned short* __restrict__ gpsS,
    unsigned short* __restrict__ img48F)
{
  int w    = (blockIdx.x * 256 + threadIdx.x) >> 6;  // one wave per row
  int lane = threadIdx.x & 63;

  f32x4 x = (f32x4){0.f, 0.f, 0.f, 0.f};
  bool isimg; int b = 0, n = 0, g = 0, m = 0;
  if (w < BB * MPAD) {
    isimg = true; b = w >> 6; n = w & 63;
    if (n < NIMG)
      x = *reinterpret_cast<const f32x4*>(img + ((size_t)b * NIMG + n) * DIM + lane * 4);
  } else {
    isimg = false; int t = w - BB * MPAD; g = t >> 5; m = t & 31;
    x = *reinterpret_cast<const f32x4*>(gps + (size_t)t * DIM + lane * 4);
  }

  float ss = x[0]*x[0] + x[1]*x[1] + x[2]*x[2] + x[3]*x[3];
  #pragma unroll
  for (int d = 1; d < 64; d <<= 1) ss += __shfl_xor(ss, d);
  float inv = (ss > 0.f) ? (1.0f / fmaxf(sqrtf(ss), 1e-12f)) : 0.f;

  unsigned int w01 = (unsigned)f2bf(x[0]*inv) | ((unsigned)f2bf(x[1]*inv) << 16);
  unsigned int w23 = (unsigned)f2bf(x[2]*inv) | ((unsigned)f2bf(x[3]*inv) << 16);

  // lane L (<32) gathers chunk L = row elems [8L, 8L+8) from lanes 2L, 2L+1
  int L = lane;
  unsigned int a0 = __shfl(w01, 2 * L);
  unsigned int a1 = __shfl(w23, 2 * L);
  unsigned int a2 = __shfl(w01, 2 * L + 1);
  unsigned int a3 = __shfl(w23, 2 * L + 1);
  if (L < 32) {
    u32x4 v = {a0, a1, a2, a3};
    if (isimg) {
      *reinterpret_cast<u32x4*>(imgS + (size_t)b * 16384 + L * 512 + n * 8) = v;
      if (n == 48 && img48F) {        // B-frag: col=b, k-chunk kc=L>>2, sub grp=L&3
        unsigned short* d48 = img48F + ((L >> 2) * 16 + (b >> 4)) * 512
                                     + ((L & 3) * 16 + (b & 15)) * 8;
        *reinterpret_cast<u32x4*>(d48) = v;
      }
    } else {
      int mt = m >> 4, c = m & 15, kc = L >> 2, grp = L & 3;
      *reinterpret_cast<u32x4*>(
          gpsS + (size_t)g * 8192 + mt * 4096 + kc * 512 + (grp * 16 + c) * 8) = v;
    }
  }
}

// ---------------- kernel 1b: S48[g][b][m] = gps[g,m] . img[b,48]  (dense MFMA) -------
// r21: 4 bt-tiles per wave with 4 INDEPENDENT accumulators (r20's single-tile serial
// acc chain was pure dependent-MFMA latency, ~13us for 0.5us of work). Per kc:
// 1 shared ga load + 4 bb loads + 4 independent MFMAs. 512 blocks (2048 waves).
__global__ __launch_bounds__(256) void gemm48_kernel(
    const unsigned short* __restrict__ gpsS, const unsigned short* __restrict__ img48F,
    float* __restrict__ S48)
{
  int wv = threadIdx.x >> 6, lane = threadIdx.x & 63;
  int id = blockIdx.x * 4 + wv;            // 0..2047
  int t  = id >> 2, q = id & 3;            // t = g*2+mt (0..511), q = bt-quad
  const unsigned short* ga = gpsS   + (size_t)t * 4096 + lane * 8;
  const unsigned short* bb = img48F + q * 2048 + lane * 8;   // 4 tiles: +j*512

  f32x4 acc[4];
  #pragma unroll
  for (int j = 0; j < 4; ++j) acc[j] = (f32x4){0.f, 0.f, 0.f, 0.f};

  #pragma unroll 2
  for (int kc = 0; kc < 8; ++kc) {
    bf16x8 a = *reinterpret_cast<const bf16x8*>(ga + kc * 512);
    bf16x8 q0 = *reinterpret_cast<const bf16x8*>(bb + kc * 8192);
    bf16x8 q1 = *reinterpret_cast<const bf16x8*>(bb + kc * 8192 + 512);
    bf16x8 q2 = *reinterpret_cast<const bf16x8*>(bb + kc * 8192 + 1024);
    bf16x8 q3 = *reinterpret_cast<const bf16x8*>(bb + kc * 8192 + 1536);
    acc[0] = __builtin_amdgcn_mfma_f32_16x16x32_bf16(a, q0, acc[0], 0, 0, 0);
    acc[1] = __builtin_amdgcn_mfma_f32_16x16x32_bf16(a, q1, acc[1], 0, 0, 0);
    acc[2] = __builtin_amdgcn_mfma_f32_16x16x32_bf16(a, q2, acc[2], 0, 0, 0);
    acc[3] = __builtin_amdgcn_mfma_f32_16x16x32_bf16(a, q3, acc[3], 0, 0, 0);
  }
  int grp = lane >> 4, c = lane & 15;
  int g = t >> 1, mbase = (t & 1) * 16 + grp * 4;
  #pragma unroll
  for (int j = 0; j < 4; ++j) {
    int b = (q * 4 + j) * 16 + c;
    *reinterpret_cast<f32x4*>(S48 + (size_t)g * 8192 + b * 32 + mbase) = acc[j];
  }
}

// ---------------- kernel 2: 3-hf pair kernel + S48 merge (r20, verified 70us) --------
__global__ __launch_bounds__(256, 4) void pair3_kernel(
    const unsigned short* __restrict__ imgS, const unsigned short* __restrict__ gpsS,
    const float* __restrict__ S48,
    float* __restrict__ i2g, float* __restrict__ g2i)
{
  int tid  = threadIdx.x;
  int wv   = tid >> 6;
  int lane = tid & 63;
  int c    = lane & 15, grp = lane >> 4;
  int b    = blockIdx.x >> 3, gc = blockIdx.x & 7;
  int wvu  = __builtin_amdgcn_readfirstlane(wv);

  __shared__ unsigned short As[8 * 3 * 64 * 8];    // [kc][hf<3][lane][8] = 24 KB

  {  // stage: wave wvu covers kc = wvu*2 + i/3, hf = i%3  (24 combos total)
    const unsigned short* src = imgS + (size_t)b * 16384;
    #pragma unroll
    for (int i = 0; i < 6; ++i) {
      int kc = wvu * 2 + (i / 3), hf = i % 3;
      bf16x8 v = *reinterpret_cast<const bf16x8*>(
          src + (kc * 4 + grp) * 512 + (hf * 16 + c) * 8);
      *reinterpret_cast<bf16x8*>(
          reinterpret_cast<char*>(As) + (kc * 3 + hf) * 1024 + lane * 16) = v;
    }
  }
  __syncthreads();

  const char* ab = reinterpret_cast<const char*>(As) + lane * 16;
  const unsigned short* gb = gpsS + ((size_t)(gc * 32 + wvu * 8)) * 8192;
  unsigned int lane8 = lane * 8;

  #pragma unroll 1
  for (int st = 0; st < 4; ++st) {
    f32x4 acc[2][2][3];                    // [g][mt][hf<3]

    {  // peeled kc=0, shared zero C
      const unsigned short* p = gb + lane8;
      bf16x8 q00 = *reinterpret_cast<const bf16x8*>(p);
      bf16x8 q01 = *reinterpret_cast<const bf16x8*>(p + 4096);
      bf16x8 q10 = *reinterpret_cast<const bf16x8*>(p + 8192);
      bf16x8 q11 = *reinterpret_cast<const bf16x8*>(p + 12288);
      bf16x8 a0 = *reinterpret_cast<const bf16x8*>(ab);
      bf16x8 a1 = *reinterpret_cast<const bf16x8*>(ab + 1024);
      bf16x8 a2 = *reinterpret_cast<const bf16x8*>(ab + 2048);
      const f32x4 Z = {0.f, 0.f, 0.f, 0.f};
      acc[0][0][0] = __builtin_amdgcn_mfma_f32_16x16x32_bf16(q00, a0, Z, 0, 0, 0);
      acc[0][0][1] = __builtin_amdgcn_mfma_f32_16x16x32_bf16(q00, a1, Z, 0, 0, 0);
      acc[0][0][2] = __builtin_amdgcn_mfma_f32_16x16x32_bf16(q00, a2, Z, 0, 0, 0);
      acc[0][1][0] = __builtin_amdgcn_mfma_f32_16x16x32_bf16(q01, a0, Z, 0, 0, 0);
      acc[0][1][1] = __builtin_amdgcn_mfma_f32_16x16x32_bf16(q01, a1, Z, 0, 0, 0);
      acc[0][1][2] = __builtin_amdgcn_mfma_f32_16x16x32_bf16(q01, a2, Z, 0, 0, 0);
      acc[1][0][0] = __builtin_amdgcn_mfma_f32_16x16x32_bf16(q10, a0, Z, 0, 0, 0);
      acc[1][0][1] = __builtin_amdgcn_mfma_f32_16x16x32_bf16(q10, a1, Z, 0, 0, 0);
      acc[1][0][2] = __builtin_amdgcn_mfma_f32_16x16x32_bf16(q10, a2, Z, 0, 0, 0);
      acc[1][1][0] = __builtin_amdgcn_mfma_f32_16x16x32_bf16(q11, a0, Z, 0, 0, 0);
      acc[1][1][1] = __builtin_amdgcn_mfma_f32_16x16x32_bf16(q11, a1, Z, 0, 0, 0);
      acc[1][1][2] = __builtin_amdgcn_mfma_f32_16x16x32_bf16(q11, a2, Z, 0, 0, 0);
    }

    #pragma unroll 1
    for (int kc = 1; kc < 8; ++kc) {
      const unsigned short* p = gb + kc * 512 + lane8;
      bf16x8 q00 = *reinterpret_cast<const bf16x8*>(p);
      bf16x8 q01 = *reinterpret_cast<const bf16x8*>(p + 4096);
      bf16x8 q10 = *reinterpret_cast<const bf16x8*>(p + 8192);
      bf16x8 q11 = *reinterpret_cast<const bf16x8*>(p + 12288);
      const char* ak = ab + kc * 3072;
      bf16x8 a0 = *reinterpret_cast<const bf16x8*>(ak);
      bf16x8 a1 = *reinterpret_cast<const bf16x8*>(ak + 1024);
      bf16x8 a2 = *reinterpret_cast<const bf16x8*>(ak + 2048);
      acc[0][0][0] = __builtin_amdgcn_mfma_f32_16x16x32_bf16(q00, a0, acc[0][0][0], 0, 0, 0);
      acc[0][0][1] = __builtin_amdgcn_mfma_f32_16x16x32_bf16(q00, a1, acc[0][0][1], 0, 0, 0);
      acc[0][0][2] = __builtin_amdgcn_mfma_f32_16x16x32_bf16(q00, a2, acc[0][0][2], 0, 0, 0);
      acc[0][1][0] = __builtin_amdgcn_mfma_f32_16x16x32_bf16(q01, a0, acc[0][1][0], 0, 0, 0);
      acc[0][1][1] = __builtin_amdgcn_mfma_f32_16x16x32_bf16(q01, a1, acc[0][1][1], 0, 0, 0);
      acc[0][1][2] = __builtin_amdgcn_mfma_f32_16x16x32_bf16(q01, a2, acc[0][1][2], 0, 0, 0);
      acc[1][0][0] = __builtin_amdgcn_mfma_f32_16x16x32_bf16(q10, a0, acc[1][0][0], 0, 0, 0);
      acc[1][0][1] = __builtin_amdgcn_mfma_f32_16x16x32_bf16(q10, a1, acc[1][0][1], 0, 0, 0);
      acc[1][0][2] = __builtin_amdgcn_mfma_f32_16x16x32_bf16(q10, a2, acc[1][0][2], 0, 0, 0);
      acc[1][1][0] = __builtin_amdgcn_mfma_f32_16x16x32_bf16(q11, a0, acc[1][1][0], 0, 0, 0);
      acc[1][1][1] = __builtin_amdgcn_mfma_f32_16x16x32_bf16(q11, a1, acc[1][1][1], 0, 0, 0);
      acc[1][1][2] = __builtin_amdgcn_mfma_f32_16x16x32_bf16(q11, a2, acc[1][1][2], 0, 0, 0);
    }

    // ---- epilogue: D = S^T, row m = mt*16+grp*4+r, col n = hf*16+c; n=48 from S48 ----
    #pragma unroll
    for (int g = 0; g < 2; ++g) {
      int gg = gc * 32 + wvu * 8 + st * 2 + g;
      const float* sp = S48 + (size_t)gg * 8192 + b * 32 + grp * 4;
      f32x4 sa = *reinterpret_cast<const f32x4*>(sp);        // m = grp*4 + r      (mt0)
      f32x4 sb = *reinterpret_cast<const f32x4*>(sp + 16);   // m = 16 + grp*4 + r (mt1)

      // i2g: mean over n<49 of (max over m)
      float vmax[3];
      #pragma unroll
      for (int hf = 0; hf < 3; ++hf) {
        float vm = fmaxf(max3f(acc[g][0][hf][0], acc[g][0][hf][1], acc[g][0][hf][2]),
                         max3f(acc[g][0][hf][3], acc[g][1][hf][0], acc[g][1][hf][1]));
        vm = max3f(vm, acc[g][1][hf][2], acc[g][1][hf][3]);
        vm = fmaxf(vm, __shfl_xor(vm, 16));
        vm = fmaxf(vm, __shfl_xor(vm, 32));
        vmax[hf] = vm;
      }
      float s = vmax[0] + vmax[1] + vmax[2];
      s = sum16(s);                          // sum over c -> cols 0..47
      float m48 = fmaxf(max3f(sa[0], sa[1], sa[2]),
                        max3f(sa[3], sb[0], sb[1]));
      m48 = max3f(m48, sb[2], sb[3]);
      m48 = fmaxf(m48, __shfl_xor(m48, 16));
      m48 = fmaxf(m48, __shfl_xor(m48, 32)); // max over m (grp spread)
      s += m48;                              // col 48's row-max

      // g2i: mean over 32 m of (max over n<49)
      float t = 0.f;
      #pragma unroll
      for (int mt = 0; mt < 2; ++mt)
        #pragma unroll
        for (int r = 0; r < 4; ++r) {
          float s48v = (mt == 0) ? sa[r] : sb[r];
          float hm = fmaxf(max3f(acc[g][mt][0][r], acc[g][mt][1][r], acc[g][mt][2][r]), s48v);
          hm = max16(hm);
          t += hm;
        }
      t += __shfl_xor(t, 16);
      t += __shfl_xor(t, 32);

      if (lane == 0) {
        i2g[b * 256 + gg] = s * (1.0f / NIMG);
        g2i[gg * 256 + b] = t * (1.0f / NGPS);
      }
    }
    gb += 16384;
  }
}

// ---------------- kernel 2 (FALLBACK = r16 verified): 4-hf pair kernel ---------------
__global__ __launch_bounds__(256, 3) void pair4_kernel(
    const unsigned short* __restrict__ imgS, const unsigned short* __restrict__ gpsS,
    float* __restrict__ i2g, float* __restrict__ g2i)
{
  int tid  = threadIdx.x;
  int wv   = tid >> 6;
  int lane = tid & 63;
  int c    = lane & 15;
  int b    = blockIdx.x >> 3, gc = blockIdx.x & 7;
  int wvu  = __builtin_amdgcn_readfirstlane(wv);

  __shared__ unsigned short As[8 * 4 * 64 * 8];    // 32 KB

  {
    const unsigned short* src = imgS + (size_t)b * 16384;
    #pragma unroll
    for (int i = 0; i < 8; ++i) {
      bf16x8 v = *reinterpret_cast<const bf16x8*>(
          src + (i * 4 + (lane >> 4)) * 512 + (wvu * 16 + (lane & 15)) * 8);
      *reinterpret_cast<bf16x8*>(
          reinterpret_cast<char*>(As) + i * 4096 + wvu * 1024 + lane * 16) = v;
    }
  }
  __syncthreads();

  const char* ab = reinterpret_cast<const char*>(As) + lane * 16;
  const unsigned short* gb = gpsS + ((size_t)(gc * 32 + wvu * 8)) * 8192;
  unsigned int lane8 = lane * 8;

  #pragma unroll 1
  for (int st = 0; st < 4; ++st) {
    f32x4 acc[2][2][4];
    {
      const unsigned short* p = gb + lane8;
      bf16x8 q00 = *reinterpret_cast<const bf16x8*>(p);
      bf16x8 q01 = *reinterpret_cast<const bf16x8*>(p + 4096);
      bf16x8 q10 = *reinterpret_cast<const bf16x8*>(p + 8192);
      bf16x8 q11 = *reinterpret_cast<const bf16x8*>(p + 12288);
      bf16x8 a0 = *reinterpret_cast<const bf16x8*>(ab);
      bf16x8 a1 = *reinterpret_cast<const bf16x8*>(ab + 1024);
      bf16x8 a2 = *reinterpret_cast<const bf16x8*>(ab + 2048);
      bf16x8 a3 = *reinterpret_cast<const bf16x8*>(ab + 3072);
      const f32x4 Z = {0.f, 0.f, 0.f, 0.f};
      acc[0][0][0] = __builtin_amdgcn_mfma_f32_16x16x32_bf16(q00, a0, Z, 0, 0, 0);
      acc[0][0][1] = __builtin_amdgcn_mfma_f32_16x16x32_bf16(q00, a1, Z, 0, 0, 0);
      acc[0][0][2] = __builtin_amdgcn_mfma_f32_16x16x32_bf16(q00, a2, Z, 0, 0, 0);
      acc[0][0][3] = __builtin_amdgcn_mfma_f32_16x16x32_bf16(q00, a3, Z, 0, 0, 0);
      acc[0][1][0] = __builtin_amdgcn_mfma_f32_16x16x32_bf16(q01, a0, Z, 0, 0, 0);
      acc[0][1][1] = __builtin_amdgcn_mfma_f32_16x16x32_bf16(q01, a1, Z, 0, 0, 0);
      acc[0][1][2] = __builtin_amdgcn_mfma_f32_16x16x32_bf16(q01, a2, Z, 0, 0, 0);
      acc[0][1][3] = __builtin_amdgcn_mfma_f32_16x16x32_bf16(q01, a3, Z, 0, 0, 0);
      acc[1][0][0] = __builtin_amdgcn_mfma_f32_16x16x32_bf16(q10, a0, Z, 0, 0, 0);
      acc[1][0][1] = __builtin_amdgcn_mfma_f32_16x16x32_bf16(q10, a1, Z, 0, 0, 0);
      acc[1][0][2] = __builtin_amdgcn_mfma_f32_16x16x32_bf16(q10, a2, Z, 0, 0, 0);
      acc[1][0][3] = __builtin_amdgcn_mfma_f32_16x16x32_bf16(q10, a3, Z, 0, 0, 0);
      acc[1][1][0] = __builtin_amdgcn_mfma_f32_16x16x32_bf16(q11, a0, Z, 0, 0, 0);
      acc[1][1][1] = __builtin_amdgcn_mfma_f32_16x16x32_bf16(q11, a1, Z, 0, 0, 0);
      acc[1][1][2] = __builtin_amdgcn_mfma_f32_16x16x32_bf16(q11, a2, Z, 0, 0, 0);
      acc[1][1][3] = __builtin_amdgcn_mfma_f32_16x16x32_bf16(q11, a3, Z, 0, 0, 0);
    }
    #pragma unroll 1
    for (int kc = 1; kc < 8; ++kc) {
      const unsigned short* p = gb + kc * 512 + lane8;
      bf16x8 q00 = *reinterpret_cast<const bf16x8*>(p);
      bf16x8 q01 = *reinterpret_cast<const bf16x8*>(p + 4096);
      bf16x8 q10 = *reinterpret_cast<const bf16x8*>(p + 8192);
      bf16x8 q11 = *reinterpret_cast<const bf16x8*>(p + 12288);
      const char* ak = ab + kc * 4096;
      bf16x8 a0 = *reinterpret_cast<const bf16x8*>(ak);
      bf16x8 a1 = *reinterpret_cast<const bf16x8*>(ak + 1024);
      bf16x8 a2 = *reinterpret_cast<const bf16x8*>(ak + 2048);
      bf16x8 a3 = *reinterpret_cast<const bf16x8*>(ak + 3072);
      acc[0][0][0] = __builtin_amdgcn_mfma_f32_16x16x32_bf16(q00, a0, acc[0][0][0], 0, 0, 0);
      acc[0][0][1] = __builtin_amdgcn_mfma_f32_16x16x32_bf16(q00, a1, acc[0][0][1], 0, 0, 0);
      acc[0][0][2] = __builtin_amdgcn_mfma_f32_16x16x32_bf16(q00, a2, acc[0][0][2], 0, 0, 0);
      acc[0][0][3] = __builtin_amdgcn_mfma_f32_16x16x32_bf16(q00, a3, acc[0][0][3], 0, 0, 0);
      acc[0][1][0] = __builtin_amdgcn_mfma_f32_16x16x32_bf16(q01, a0, acc[0][1][0], 0, 0, 0);
      acc[0][1][1] = __builtin_amdgcn_mfma_f32_16x16x32_bf16(q01, a1, acc[0][1][1], 0, 0, 0);
      acc[0][1][2] = __builtin_amdgcn_mfma_f32_16x16x32_bf16(q01, a2, acc[0][1][2], 0, 0, 0);
      acc[0][1][3] = __builtin_amdgcn_mfma_f32_16x16x32_bf16(q01, a3, acc[0][1][3], 0, 0, 0);
      acc[1][0][0] = __builtin_amdgcn_mfma_f32_16x16x32_bf16(q10, a0, acc[1][0][0], 0, 0, 0);
      acc[1][0][1] = __builtin_amdgcn_mfma_f32_16x16x32_bf16(q10, a1, acc[1][0][1], 0, 0, 0);
      acc[1][0][2] = __builtin_amdgcn_mfma_f32_16x16x32_bf16(q10, a2, acc[1][0][2], 0, 0, 0);
      acc[1][0][3] = __builtin_amdgcn_mfma_f32_16x16x32_bf16(q10, a3, acc[1][0][3], 0, 0, 0);
      acc[1][1][0] = __builtin_amdgcn_mfma_f32_16x16x32_bf16(q11, a0, acc[1][1][0], 0, 0, 0);
      acc[1][1][1] = __builtin_amdgcn_mfma_f32_16x16x32_bf16(q11, a1, acc[1][1][1], 0, 0, 0);
      acc[1][1][2] = __builtin_amdgcn_mfma_f32_16x16x32_bf16(q11, a2, acc[1][1][2], 0, 0, 0);
      acc[1][1][3] = __builtin_amdgcn_mfma_f32_16x16x32_bf16(q11, a3, acc[1][1][3], 0, 0, 0);
    }
    #pragma unroll
    for (int g = 0; g < 2; ++g) {
      float vmax[4];
      #pragma unroll
      for (int hf = 0; hf < 4; ++hf) {
        float vm = fmaxf(max3f(acc[g][0][hf][0], acc[g][0][hf][1], acc[g][0][hf][2]),
                         max3f(acc[g][0][hf][3], acc[g][1][hf][0], acc[g][1][hf][1]));
        vm = max3f(vm, acc[g][1][hf][2], acc[g][1][hf][3]);
        vm = fmaxf(vm, __shfl_xor(vm, 16));
        vm = fmaxf(vm, __shfl_xor(vm, 32));
        vmax[hf] = vm;
      }
      float s = vmax[0] + vmax[1] + vmax[2] + ((c == 0) ? vmax[3] : 0.0f);
      s = sum16(s);
      float t = 0.f;
      #pragma unroll
      for (int mt = 0; mt < 2; ++mt)
        #pragma unroll
        for (int r = 0; r < 4; ++r) {
          float h3 = (c == 0) ? acc[g][mt][3][r] : -3.0e38f;
          float hm = fmaxf(max3f(acc[g][mt][0][r], acc[g][mt][1][r], acc[g][mt][2][r]), h3);
          hm = max16(hm);
          t += hm;
        }
      t += __shfl_xor(t, 16);
      t += __shfl_xor(t, 32);
      if (lane == 0) {
        int gg = gc * 32 + wvu * 8 + st * 2 + g;
        i2g[b * 256 + gg] = s * (1.0f / NIMG);
        g2i[gg * 256 + b] = t * (1.0f / NGPS);
      }
    }
    gb += 16384;
  }
}

// ---------------- kernel 3: per-row CE partials -------------------------------------
__global__ __launch_bounds__(256) void ce_kernel(
    const float* __restrict__ i2g, const float* __restrict__ g2i,
    const float* __restrict__ lsp, float* __restrict__ partial)
{
  int b = blockIdx.x, t = threadIdx.x, lane = t & 63, wv = t >> 6;
  float s = fminf(expf(lsp[0]), 100.0f);
  float v1 = s * i2g[b * 256 + t];
  float v2 = s * g2i[b * 256 + t];

  float m1 = v1, m2 = v2;
  #pragma unroll
  for (int d = 1; d < 64; d <<= 1) {
    m1 = fmaxf(m1, __shfl_xor(m1, d));
    m2 = fmaxf(m2, __shfl_xor(m2, d));
  }
  __shared__ float sm[2][4];
  if (lane == 0) { sm[0][wv] = m1; sm[1][wv] = m2; }
  __syncthreads();
  m1 = fmaxf(fmaxf(sm[0][0], sm[0][1]), fmaxf(sm[0][2], sm[0][3]));
  m2 = fmaxf(fmaxf(sm[1][0], sm[1][1]), fmaxf(sm[1][2], sm[1][3]));

  float e1 = expf(v1 - m1), e2 = expf(v2 - m2);
  #pragma unroll
  for (int d = 1; d < 64; d <<= 1) {
    e1 += __shfl_xor(e1, d);
    e2 += __shfl_xor(e2, d);
  }
  __shared__ float se[2][4];
  if (lane == 0) { se[0][wv] = e1; se[1][wv] = e2; }
  __syncthreads();
  if (t == 0) {
    float S1 = se[0][0] + se[0][1] + se[0][2] + se[0][3];
    float S2 = se[1][0] + se[1][1] + se[1][2] + se[1][3];
    float lse1 = m1 + logf(S1);
    float lse2 = m2 + logf(S2);
    partial[b] = (lse1 - s * i2g[b * 257]) + (lse2 - s * g2i[b * 257]);
  }
}

// ---------------- kernel 4: final scalar --------------------------------------------
__global__ __launch_bounds__(256) void finish_kernel(
    const float* __restrict__ partial, float* __restrict__ out)
{
  int t = threadIdx.x, lane = t & 63, wv = t >> 6;
  float v = partial[t];
  #pragma unroll
  for (int d = 1; d < 64; d <<= 1) v += __shfl_xor(v, d);
  __shared__ float sp[4];
  if (lane == 0) sp[wv] = v;
  __syncthreads();
  if (t == 0) out[0] = (sp[0] + sp[1] + sp[2] + sp[3]) * (1.0f / 512.0f);
}

extern "C" void kernel_launch(void* const* d_in, const int* in_sizes, int n_in,
                              void* d_out, int out_size, void* d_ws, size_t ws_size,
                              hipStream_t stream)
{
  const float* img = (const float*)d_in[0];
  const float* gps = (const float*)d_in[1];
  const float* lsp = (const float*)d_in[2];
  float* out = (float*)d_out;
  char* ws = (char*)d_ws;

  // New-path layout (needs 21,627,904 B). Falls back to r16 path if ws too small.
  const size_t NEED = 21627904;
  unsigned short* imgS = (unsigned short*)(ws);               //  8,388,608
  unsigned short* gpsS = (unsigned short*)(ws + 8388608);     //  4,194,304

  if (ws_size >= NEED) {
    unsigned short* img48F = (unsigned short*)(ws + 12582912); //   131,072
    float* S48     = (float*)(ws + 12713984);                  // 8,388,608
    float* i2g     = (float*)(ws + 21102592);                  //   262,144
    float* g2i     = (float*)(ws + 21364736);                  //   262,144
    float* partial = (float*)(ws + 21626880);                  //     1,024
    norm_kernel<<<6144, 256, 0, stream>>>(img, gps, imgS, gpsS, img48F);
    gemm48_kernel<<<512, 256, 0, stream>>>(gpsS, img48F, S48);
    pair3_kernel<<<2048, 256, 0, stream>>>(imgS, gpsS, S48, i2g, g2i);
    ce_kernel<<<256, 256, 0, stream>>>(i2g, g2i, lsp, partial);
    finish_kernel<<<1, 256, 0, stream>>>(partial, out);
  } else {
    float* i2g     = (float*)(ws + 12582912);
    float* g2i     = (float*)(ws + 12845056);
    float* partial = (float*)(ws + 13107200);
    norm_kernel<<<6144, 256, 0, stream>>>(img, gps, imgS, gpsS, nullptr);
    pair4_kernel<<<2048, 256, 0, stream>>>(imgS, gpsS, i2g, g2i);
    ce_kernel<<<256, 256, 0, stream>>>(i2g, g2i, lsp, partial);
    finish_kernel<<<1, 256, 0, stream>>>(partial, out);
  }
}

// Round 22
// 85.346 us; speedup vs baseline: 1.0521x; 1.0473x over previous
//
#include <hip/hip_runtime.h>

#define BB   256
#define NIMG 49
#define NGPS 32
#define DIM  256
#define MPAD 64

typedef __attribute__((ext_vector_type(8))) __bf16 bf16x8;
typedef __attribute__((ext_vector_type(4))) float  f32x4;
typedef __attribute__((ext_vector_type(4))) unsigned int u32x4;

__device__ inline unsigned short f2bf(float f) {
  unsigned int u = __float_as_uint(f);
  u += 0x7fff + ((u >> 16) & 1);   // round-to-nearest-even
  return (unsigned short)(u >> 16);
}

__device__ inline float max3f(float a, float b, float c) {
  return fmaxf(fmaxf(a, b), c);    // clang folds to v_max3_f32
}

// DPP cross-lane reduce helpers (VALU pipe, no DS traffic).
template<int CTRL>
__device__ inline float dppmax(float v) {
  float o = __int_as_float(__builtin_amdgcn_update_dpp(0, __float_as_int(v), CTRL, 0xF, 0xF, true));
  return fmaxf(v, o);
}
template<int CTRL>
__device__ inline float dppadd(float v) {
  float o = __int_as_float(__builtin_amdgcn_update_dpp(0, __float_as_int(v), CTRL, 0xF, 0xF, true));
  return v + o;
}
__device__ inline float max16(float v) {   // max across the 16 lanes of a DPP row
  v = dppmax<0xB1>(v); v = dppmax<0x4E>(v); v = dppmax<0x141>(v); v = dppmax<0x140>(v);
  return v;
}
__device__ inline float sum16(float v) {   // sum across the 16 lanes of a DPP row
  v = dppadd<0xB1>(v); v = dppadd<0x4E>(v); v = dppadd<0x141>(v); v = dppadd<0x140>(v);
  return v;
}

// ---------------- kernel 1: L2-normalize + cast to bf16, FRAGMENT-CONTIGUOUS layout --
// (r9 win: +44%. Every hot-loop global load is `lane i reads base + i*16B`.)
//   imgS[b][chunk s=0..31][row 0..63][8 bf16]  (b stride 16384 elem)
//   gpsS[g][mt][kc][grp*16+c][8 bf16]          (g stride 8192 elem)
__global__ __launch_bounds__(256) void norm_kernel(
    const float* __restrict__ img, const float* __restrict__ gps,
    unsigned short* __restrict__ imgS, unsigned short* __restrict__ gpsS)
{
  int w    = (blockIdx.x * 256 + threadIdx.x) >> 6;  // one wave per row
  int lane = threadIdx.x & 63;

  f32x4 x = (f32x4){0.f, 0.f, 0.f, 0.f};
  bool isimg; int b = 0, n = 0, g = 0, m = 0;
  if (w < BB * MPAD) {
    isimg = true; b = w >> 6; n = w & 63;
    if (n < NIMG)
      x = *reinterpret_cast<const f32x4*>(img + ((size_t)b * NIMG + n) * DIM + lane * 4);
  } else {
    isimg = false; int t = w - BB * MPAD; g = t >> 5; m = t & 31;
    x = *reinterpret_cast<const f32x4*>(gps + (size_t)t * DIM + lane * 4);
  }

  float ss = x[0]*x[0] + x[1]*x[1] + x[2]*x[2] + x[3]*x[3];
  #pragma unroll
  for (int d = 1; d < 64; d <<= 1) ss += __shfl_xor(ss, d);
  float inv = (ss > 0.f) ? (1.0f / fmaxf(sqrtf(ss), 1e-12f)) : 0.f;

  // pack this lane's 4 bf16 (elems lane*4 .. lane*4+3) into two u32
  unsigned int w01 = (unsigned)f2bf(x[0]*inv) | ((unsigned)f2bf(x[1]*inv) << 16);
  unsigned int w23 = (unsigned)f2bf(x[2]*inv) | ((unsigned)f2bf(x[3]*inv) << 16);

  // lane L (<32) gathers chunk L = row elems [8L, 8L+8) from lanes 2L, 2L+1
  int L = lane;
  unsigned int a0 = __shfl(w01, 2 * L);
  unsigned int a1 = __shfl(w23, 2 * L);
  unsigned int a2 = __shfl(w01, 2 * L + 1);
  unsigned int a3 = __shfl(w23, 2 * L + 1);
  if (L < 32) {
    u32x4 v = {a0, a1, a2, a3};
    unsigned short* dst;
    if (isimg) {
      dst = imgS + (size_t)b * 16384 + L * 512 + n * 8;          // [b][s=L][row n]
    } else {
      int mt = m >> 4, c = m & 15, kc = L >> 2, grp = L & 3;
      dst = gpsS + (size_t)g * 8192 + mt * 4096 + kc * 512 + (grp * 16 + c) * 8;
    }
    *reinterpret_cast<u32x4*>(dst) = v;
  }
}

// ---------------- kernel 2: all-pairs MFMA + fused max/mean reductions --------------
// grid: 2048 blocks = 256 b * 8 g-chunks; 4 waves/block, 2 g's per wave step.
// A (img[b], 64x256 bf16 = 32KB) staged once in LDS in FRAGMENT-CONTIGUOUS layout
// As[kc][hf][lane][16B]: hot-loop ds_read_b128 = base reg + offset. Bank
// conflicts = 0 (verified r14/r16), zero addressing VALU.
// FINAL STATE (r21 revert): this is the verified-best structure (84.4-84.9us
// total, pair 76us, 904 TF effective). Measured-null levers: traffic halving
// (r8), reg headroom (r12), VALU cuts (r16: worked mechanically, time-neutral),
// burst depth x2 (r19), occupancy force (r10), hf3-split (r20/21: pair -6us but
// +10us pipeline overhead -> net negative). Spill triggers to avoid: forcing
// (256,3+) with >170 combined regs (r3/r6/r14), unroll>=2 with cheap addressing
// (r14), prefetch arrays (r5). kc `unroll 1` IS the liveness throttle.
__global__ __launch_bounds__(256, 3) void pair_kernel(
    const unsigned short* __restrict__ imgS, const unsigned short* __restrict__ gpsS,
    float* __restrict__ i2g, float* __restrict__ g2i)
{
  int tid  = threadIdx.x;
  int wv   = tid >> 6;
  int lane = tid & 63;
  int c    = lane & 15;
  int b    = blockIdx.x >> 3, gc = blockIdx.x & 7;
  int wvu  = __builtin_amdgcn_readfirstlane(wv);   // wave-uniform -> SGPR

  __shared__ unsigned short As[8 * 4 * 64 * 8];    // [kc][hf][lane][8] = 32 KB

  // ---- stage A: global [b][s=kc*4+grp][n=hf*16+c] -> LDS [kc][hf][grp*16+c] ----
  {
    const unsigned short* src = imgS + (size_t)b * 16384;
    #pragma unroll
    for (int i = 0; i < 8; ++i) {
      bf16x8 v = *reinterpret_cast<const bf16x8*>(
          src + (i * 4 + (lane >> 4)) * 512 + (wvu * 16 + (lane & 15)) * 8);
      *reinterpret_cast<bf16x8*>(
          reinterpret_cast<char*>(As) + i * 4096 + wvu * 1024 + lane * 16) = v;
    }
  }
  __syncthreads();

  const char* ab = reinterpret_cast<const char*>(As) + lane * 16;

  // wave-uniform gps tile base (SGPR) + single per-lane element offset
  const unsigned short* gb = gpsS + ((size_t)(gc * 32 + wvu * 8)) * 8192;
  unsigned int lane8 = lane * 8;

  #pragma unroll 1
  for (int st = 0; st < 4; ++st) {
    f32x4 acc[2][2][4];                        // [g][mt (gps rows)][hf (img cols)]

    // ---- peeled kc = 0: C = shared zero vector (no per-acc zero-init) ----
    {
      const unsigned short* p = gb + lane8;
      bf16x8 q00 = *reinterpret_cast<const bf16x8*>(p);
      bf16x8 q01 = *reinterpret_cast<const bf16x8*>(p + 4096);
      bf16x8 q10 = *reinterpret_cast<const bf16x8*>(p + 8192);
      bf16x8 q11 = *reinterpret_cast<const bf16x8*>(p + 12288);
      bf16x8 a0 = *reinterpret_cast<const bf16x8*>(ab);
      bf16x8 a1 = *reinterpret_cast<const bf16x8*>(ab + 1024);
      bf16x8 a2 = *reinterpret_cast<const bf16x8*>(ab + 2048);
      bf16x8 a3 = *reinterpret_cast<const bf16x8*>(ab + 3072);
      const f32x4 Z = {0.f, 0.f, 0.f, 0.f};
      acc[0][0][0] = __builtin_amdgcn_mfma_f32_16x16x32_bf16(q00, a0, Z, 0, 0, 0);
      acc[0][0][1] = __builtin_amdgcn_mfma_f32_16x16x32_bf16(q00, a1, Z, 0, 0, 0);
      acc[0][0][2] = __builtin_amdgcn_mfma_f32_16x16x32_bf16(q00, a2, Z, 0, 0, 0);
      acc[0][0][3] = __builtin_amdgcn_mfma_f32_16x16x32_bf16(q00, a3, Z, 0, 0, 0);
      acc[0][1][0] = __builtin_amdgcn_mfma_f32_16x16x32_bf16(q01, a0, Z, 0, 0, 0);
      acc[0][1][1] = __builtin_amdgcn_mfma_f32_16x16x32_bf16(q01, a1, Z, 0, 0, 0);
      acc[0][1][2] = __builtin_amdgcn_mfma_f32_16x16x32_bf16(q01, a2, Z, 0, 0, 0);
      acc[0][1][3] = __builtin_amdgcn_mfma_f32_16x16x32_bf16(q01, a3, Z, 0, 0, 0);
      acc[1][0][0] = __builtin_amdgcn_mfma_f32_16x16x32_bf16(q10, a0, Z, 0, 0, 0);
      acc[1][0][1] = __builtin_amdgcn_mfma_f32_16x16x32_bf16(q10, a1, Z, 0, 0, 0);
      acc[1][0][2] = __builtin_amdgcn_mfma_f32_16x16x32_bf16(q10, a2, Z, 0, 0, 0);
      acc[1][0][3] = __builtin_amdgcn_mfma_f32_16x16x32_bf16(q10, a3, Z, 0, 0, 0);
      acc[1][1][0] = __builtin_amdgcn_mfma_f32_16x16x32_bf16(q11, a0, Z, 0, 0, 0);
      acc[1][1][1] = __builtin_amdgcn_mfma_f32_16x16x32_bf16(q11, a1, Z, 0, 0, 0);
      acc[1][1][2] = __builtin_amdgcn_mfma_f32_16x16x32_bf16(q11, a2, Z, 0, 0, 0);
      acc[1][1][3] = __builtin_amdgcn_mfma_f32_16x16x32_bf16(q11, a3, Z, 0, 0, 0);
    }

    #pragma unroll 1
    for (int kc = 1; kc < 8; ++kc) {
      const unsigned short* p = gb + kc * 512 + lane8;
      bf16x8 q00 = *reinterpret_cast<const bf16x8*>(p);
      bf16x8 q01 = *reinterpret_cast<const bf16x8*>(p + 4096);
      bf16x8 q10 = *reinterpret_cast<const bf16x8*>(p + 8192);
      bf16x8 q11 = *reinterpret_cast<const bf16x8*>(p + 12288);
      const char* ak = ab + kc * 4096;
      bf16x8 a0 = *reinterpret_cast<const bf16x8*>(ak);
      bf16x8 a1 = *reinterpret_cast<const bf16x8*>(ak + 1024);
      bf16x8 a2 = *reinterpret_cast<const bf16x8*>(ak + 2048);
      bf16x8 a3 = *reinterpret_cast<const bf16x8*>(ak + 3072);
      acc[0][0][0] = __builtin_amdgcn_mfma_f32_16x16x32_bf16(q00, a0, acc[0][0][0], 0, 0, 0);
      acc[0][0][1] = __builtin_amdgcn_mfma_f32_16x16x32_bf16(q00, a1, acc[0][0][1], 0, 0, 0);
      acc[0][0][2] = __builtin_amdgcn_mfma_f32_16x16x32_bf16(q00, a2, acc[0][0][2], 0, 0, 0);
      acc[0][0][3] = __builtin_amdgcn_mfma_f32_16x16x32_bf16(q00, a3, acc[0][0][3], 0, 0, 0);
      acc[0][1][0] = __builtin_amdgcn_mfma_f32_16x16x32_bf16(q01, a0, acc[0][1][0], 0, 0, 0);
      acc[0][1][1] = __builtin_amdgcn_mfma_f32_16x16x32_bf16(q01, a1, acc[0][1][1], 0, 0, 0);
      acc[0][1][2] = __builtin_amdgcn_mfma_f32_16x16x32_bf16(q01, a2, acc[0][1][2], 0, 0, 0);
      acc[0][1][3] = __builtin_amdgcn_mfma_f32_16x16x32_bf16(q01, a3, acc[0][1][3], 0, 0, 0);
      acc[1][0][0] = __builtin_amdgcn_mfma_f32_16x16x32_bf16(q10, a0, acc[1][0][0], 0, 0, 0);
      acc[1][0][1] = __builtin_amdgcn_mfma_f32_16x16x32_bf16(q10, a1, acc[1][0][1], 0, 0, 0);
      acc[1][0][2] = __builtin_amdgcn_mfma_f32_16x16x32_bf16(q10, a2, acc[1][0][2], 0, 0, 0);
      acc[1][0][3] = __builtin_amdgcn_mfma_f32_16x16x32_bf16(q10, a3, acc[1][0][3], 0, 0, 0);
      acc[1][1][0] = __builtin_amdgcn_mfma_f32_16x16x32_bf16(q11, a0, acc[1][1][0], 0, 0, 0);
      acc[1][1][1] = __builtin_amdgcn_mfma_f32_16x16x32_bf16(q11, a1, acc[1][1][1], 0, 0, 0);
      acc[1][1][2] = __builtin_amdgcn_mfma_f32_16x16x32_bf16(q11, a2, acc[1][1][2], 0, 0, 0);
      acc[1][1][3] = __builtin_amdgcn_mfma_f32_16x16x32_bf16(q11, a3, acc[1][1][3], 0, 0, 0);
    }

    // ---- epilogue per g: D = S^T, row m = mt*16+grp*4+r (gps), col n = hf*16+c ----
    #pragma unroll
    for (int g = 0; g < 2; ++g) {
      // i2g: mean over n<49 of (max over m). max over m: in-lane (mt,r) + xor16/32.
      float vmax[4];
      #pragma unroll
      for (int hf = 0; hf < 4; ++hf) {
        float vm = fmaxf(max3f(acc[g][0][hf][0], acc[g][0][hf][1], acc[g][0][hf][2]),
                         max3f(acc[g][0][hf][3], acc[g][1][hf][0], acc[g][1][hf][1]));
        vm = max3f(vm, acc[g][1][hf][2], acc[g][1][hf][3]);
        vm = fmaxf(vm, __shfl_xor(vm, 16));
        vm = fmaxf(vm, __shfl_xor(vm, 32));
        vmax[hf] = vm;
      }
      // valid n: hf<3 all 16 c's; hf==3 only c==0 (n=48)
      float s = vmax[0] + vmax[1] + vmax[2] + ((c == 0) ? vmax[3] : 0.0f);
      s = sum16(s);                            // sum over c -> sum over n<49

      // g2i: mean over 32 m of (max over n<49). in-lane over hf (mask hf3), max16
      // over c, then sum over (mt,r) in-lane + xor16/32 over grp.
      float t = 0.f;
      #pragma unroll
      for (int mt = 0; mt < 2; ++mt)
        #pragma unroll
        for (int r = 0; r < 4; ++r) {
          float h3 = (c == 0) ? acc[g][mt][3][r] : -3.0e38f;
          float hm = fmaxf(max3f(acc[g][mt][0][r], acc[g][mt][1][r], acc[g][mt][2][r]), h3);
          hm = max16(hm);
          t += hm;
        }
      t += __shfl_xor(t, 16);
      t += __shfl_xor(t, 32);

      if (lane == 0) {
        int gg = gc * 32 + wvu * 8 + st * 2 + g;
        i2g[b * 256 + gg] = s * (1.0f / NIMG);
        g2i[gg * 256 + b] = t * (1.0f / NGPS);
      }
    }
    gb += 16384;                               // advance 2 g tiles (2*8192 elems)
  }
}

// ---------------- kernel 3: per-row CE partials -------------------------------------
__global__ __launch_bounds__(256) void ce_kernel(
    const float* __restrict__ i2g, const float* __restrict__ g2i,
    const float* __restrict__ lsp, float* __restrict__ partial)
{
  int b = blockIdx.x, t = threadIdx.x, lane = t & 63, wv = t >> 6;
  float s = fminf(expf(lsp[0]), 100.0f);
  float v1 = s * i2g[b * 256 + t];
  float v2 = s * g2i[b * 256 + t];

  float m1 = v1, m2 = v2;
  #pragma unroll
  for (int d = 1; d < 64; d <<= 1) {
    m1 = fmaxf(m1, __shfl_xor(m1, d));
    m2 = fmaxf(m2, __shfl_xor(m2, d));
  }
  __shared__ float sm[2][4];
  if (lane == 0) { sm[0][wv] = m1; sm[1][wv] = m2; }
  __syncthreads();
  m1 = fmaxf(fmaxf(sm[0][0], sm[0][1]), fmaxf(sm[0][2], sm[0][3]));
  m2 = fmaxf(fmaxf(sm[1][0], sm[1][1]), fmaxf(sm[1][2], sm[1][3]));

  float e1 = expf(v1 - m1), e2 = expf(v2 - m2);
  #pragma unroll
  for (int d = 1; d < 64; d <<= 1) {
    e1 += __shfl_xor(e1, d);
    e2 += __shfl_xor(e2, d);
  }
  __shared__ float se[2][4];
  if (lane == 0) { se[0][wv] = e1; se[1][wv] = e2; }
  __syncthreads();
  if (t == 0) {
    float S1 = se[0][0] + se[0][1] + se[0][2] + se[0][3];
    float S2 = se[1][0] + se[1][1] + se[1][2] + se[1][3];
    float lse1 = m1 + logf(S1);
    float lse2 = m2 + logf(S2);
    partial[b] = (lse1 - s * i2g[b * 257]) + (lse2 - s * g2i[b * 257]);
  }
}

// ---------------- kernel 4: final scalar --------------------------------------------
__global__ __launch_bounds__(256) void finish_kernel(
    const float* __restrict__ partial, float* __restrict__ out)
{
  int t = threadIdx.x, lane = t & 63, wv = t >> 6;
  float v = partial[t];
  #pragma unroll
  for (int d = 1; d < 64; d <<= 1) v += __shfl_xor(v, d);
  __shared__ float sp[4];
  if (lane == 0) sp[wv] = v;
  __syncthreads();
  if (t == 0) out[0] = (sp[0] + sp[1] + sp[2] + sp[3]) * (1.0f / 512.0f);
}

extern "C" void kernel_launch(void* const* d_in, const int* in_sizes, int n_in,
                              void* d_out, int out_size, void* d_ws, size_t ws_size,
                              hipStream_t stream)
{
  const float* img = (const float*)d_in[0];
  const float* gps = (const float*)d_in[1];
  const float* lsp = (const float*)d_in[2];
  float* out = (float*)d_out;
  char* ws = (char*)d_ws;

  unsigned short* imgS = (unsigned short*)(ws);              //  8,388,608 B
  unsigned short* gpsS = (unsigned short*)(ws + 8388608);    //  4,194,304 B
  float* i2g     = (float*)(ws + 12582912);                  //    262,144 B
  float* g2i     = (float*)(ws + 12845056);                  //    262,144 B
  float* partial = (float*)(ws + 13107200);                  //      1,024 B

  norm_kernel<<<6144, 256, 0, stream>>>(img, gps, imgS, gpsS);
  pair_kernel<<<2048, 256, 0, stream>>>(imgS, gpsS, i2g, g2i);
  ce_kernel<<<256, 256, 0, stream>>>(i2g, g2i, lsp, partial);
  finish_kernel<<<1, 256, 0, stream>>>(partial, out);
}